// Round 8
// baseline (940.380 us; speedup 1.0000x reference)
//
#include <hip/hip_runtime.h>

#define HW 2304
#define W48 48
#define NT 15              // timestep partials for the atomic spread

// ---------------------------------------------------------------------------
// prep: build rec_ext (float4: c0,c1,c2,walls) for all 16 timesteps,
//       build cur0 (frame 0 + walls), copy frame 0 (3ch) to d_out.
// ---------------------------------------------------------------------------
__global__ __launch_bounds__(256) void prep_kernel(
    const float* __restrict__ x, const float* __restrict__ rec,
    const float* __restrict__ walls,
    float4* __restrict__ rec4, float4* __restrict__ cur0,
    float* __restrict__ dout)
{
    int id = blockIdx.x * 256 + threadIdx.x;
    if (id < 16 * HW) {
        int t = id / HW, p = id % HW;
        rec4[id] = make_float4(rec[(t * 3 + 0) * HW + p],
                               rec[(t * 3 + 1) * HW + p],
                               rec[(t * 3 + 2) * HW + p],
                               walls[p]);
    }
    if (id < HW) {
        cur0[id] = make_float4(x[0 * HW + id], x[1 * HW + id], x[2 * HW + id],
                               walls[id]);
    }
    if (id < 3 * HW) {
        dout[id] = x[id];  // frame 0, channels 0..2
    }
}

// DPP row-shift-left by N within 16-lane rows: lane i <- lane i+N
// (rocPRIM-verified direction: row_shr:N = i<-i-N, so row_shl:N = i<-i+N).
template <int CTL>
__device__ __forceinline__ float dppf(float v)
{
    return __int_as_float(__builtin_amdgcn_update_dpp(
        0, __float_as_int(v), CTL, 0xF, 0xF, false));
}

// ---------------------------------------------------------------------------
// dist v8: wave-autonomous. 2880 blocks x 64 threads, one wave per
// (t, sy, 12-row output strip). NO LDS, NO barriers.
// lane = (c = lane>>4, r = lane&15): owns F/R row y0-2+r, cols 12c..12c+11.
//  - rec cols slide through a 12-slot NAMED register ring (12 stamped
//    rotations, literal indices; refill 1 col/sx from L2).
//  - F col-halo (x0-2,-1,+12,+13) via 4 ds_bpermute from lanes +-16.
//  - 5-tap column sums via v_add_f32 + DPP row_shl:1..4 (lanes r..r+4 live
//    in one 16-lane DPP row; valid outputs r=0..11). Exact left-assoc order.
// Distances bit-identical to rounds 2..7 (same exprs, same order); packed
// (d_bits<<32|idx) u64 running min + atomicMin to per-t partials.
// ---------------------------------------------------------------------------
__global__ __launch_bounds__(64, 3) void dist_kernel(
    const float4* __restrict__ rec4, const float4* __restrict__ cur4,
    unsigned long long* __restrict__ best_part)
{
    const int b     = blockIdx.x;
    const int t     = b / 192;
    const int rem   = b % 192;
    const int sy    = rem >> 2;
    const int y0    = (rem & 3) * 12;

    const int lane = threadIdx.x;
    const int c    = lane >> 4;
    const int r    = lane & 15;
    const int x0   = 12 * c;

    int Frow = y0 - 2 + r;
    if (Frow < 0) Frow += W48;
    if (Frow >= W48) Frow -= W48;
    int ry = Frow + sy;
    if (ry >= W48) ry -= W48;

    int orow = y0 + r + sy;            // output candidate row (valid r<12)
    if (orow >= W48) orow -= W48;
    if (orow >= W48) orow -= W48;
    const unsigned int mb = (unsigned int)(t * HW + orow * W48);

    const int addrL = ((lane + 48) & 63) << 2;   // c-1 neighbor (same r)
    const int addrR = ((lane + 16) & 63) << 2;   // c+1 neighbor (same r)

    const float4* curRow = cur4 + Frow * W48;
    const float4* recRow = rec4 + t * HW + ry * W48;

    const float4 cw0  = curRow[x0 + 0];
    const float4 cw1  = curRow[x0 + 1];
    const float4 cw2  = curRow[x0 + 2];
    const float4 cw3  = curRow[x0 + 3];
    const float4 cw4  = curRow[x0 + 4];
    const float4 cw5  = curRow[x0 + 5];
    const float4 cw6  = curRow[x0 + 6];
    const float4 cw7  = curRow[x0 + 7];
    const float4 cw8  = curRow[x0 + 8];
    const float4 cw9  = curRow[x0 + 9];
    const float4 cw10 = curRow[x0 + 10];
    const float4 cw11 = curRow[x0 + 11];

    float4 q0  = recRow[x0 + 0];
    float4 q1  = recRow[x0 + 1];
    float4 q2  = recRow[x0 + 2];
    float4 q3  = recRow[x0 + 3];
    float4 q4  = recRow[x0 + 4];
    float4 q5  = recRow[x0 + 5];
    float4 q6  = recRow[x0 + 6];
    float4 q7  = recRow[x0 + 7];
    float4 q8  = recRow[x0 + 8];
    float4 q9  = recRow[x0 + 9];
    float4 q10 = recRow[x0 + 10];
    float4 q11 = recRow[x0 + 11];

    int nc = x0 + 12; if (nc >= W48) nc -= W48;  // next ring col to fetch
    int xs = x0;                                  // (x0 + sx) % 48

    unsigned long long bst[12];
#pragma unroll
    for (int i = 0; i < 12; i++) bst[i] = ~0ULL;

#define DIFF(D, C, Wv) do {                                                 \
        float d0 = (C).x - (Wv).x, d1 = (C).y - (Wv).y,                     \
              d2 = (C).z - (Wv).z, d3 = (C).w - (Wv).w;                     \
        D = d0 * d0 + d1 * d1 + d2 * d2 + d3 * d3;                          \
    } while (0)

#define COLJ(J, RJ) do {                                                    \
        float a_ = RJ + dppf<0x101>(RJ);                                    \
        a_ = a_ + dppf<0x102>(RJ);                                          \
        a_ = a_ + dppf<0x103>(RJ);                                          \
        float D_ = a_ + dppf<0x104>(RJ);                                    \
        int rxw_ = xs + (J); if (rxw_ >= W48) rxw_ -= W48;                  \
        unsigned long long pk_ =                                            \
            ((unsigned long long)__float_as_uint(D_) << 32) |               \
            (mb + (unsigned)rxw_);                                          \
        bst[J] = pk_ < bst[J] ? pk_ : bst[J];                               \
    } while (0)

#define STEP(A0,A1,A2,A3,A4,A5,A6,A7,A8,A9,A10,A11) do {                    \
        float F0, F1, F2, F3, F4, F5, F6, F7, F8, F9, F10, F11;             \
        DIFF(F0,  cw0,  A0);  DIFF(F1,  cw1,  A1);                          \
        DIFF(F10, cw10, A10); DIFF(F11, cw11, A11);                         \
        float Fm2 = __int_as_float(                                         \
            __builtin_amdgcn_ds_bpermute(addrL, __float_as_int(F10)));      \
        float Fm1 = __int_as_float(                                         \
            __builtin_amdgcn_ds_bpermute(addrL, __float_as_int(F11)));      \
        float F12 = __int_as_float(                                         \
            __builtin_amdgcn_ds_bpermute(addrR, __float_as_int(F0)));       \
        float F13 = __int_as_float(                                         \
            __builtin_amdgcn_ds_bpermute(addrR, __float_as_int(F1)));       \
        A0 = recRow[nc];                    /* refill retiring slot */      \
        nc++; if (nc >= W48) nc -= W48;                                     \
        DIFF(F2, cw2, A2); DIFF(F3, cw3, A3); DIFF(F4, cw4, A4);            \
        DIFF(F5, cw5, A5); DIFF(F6, cw6, A6); DIFF(F7, cw7, A7);            \
        DIFF(F8, cw8, A8); DIFF(F9, cw9, A9);                               \
        float R0  = Fm2 + Fm1 + F0 + F1 + F2;                               \
        float R1  = Fm1 + F0 + F1 + F2 + F3;                                \
        float R2  = F0 + F1 + F2 + F3 + F4;                                 \
        float R3  = F1 + F2 + F3 + F4 + F5;                                 \
        float R4  = F2 + F3 + F4 + F5 + F6;                                 \
        float R5  = F3 + F4 + F5 + F6 + F7;                                 \
        float R6  = F4 + F5 + F6 + F7 + F8;                                 \
        float R7  = F5 + F6 + F7 + F8 + F9;                                 \
        float R8  = F6 + F7 + F8 + F9 + F10;                                \
        float R9  = F7 + F8 + F9 + F10 + F11;                               \
        float R10 = F8 + F9 + F10 + F11 + F12;                              \
        float R11 = F9 + F10 + F11 + F12 + F13;                             \
        COLJ(0, R0);  COLJ(1, R1);  COLJ(2, R2);  COLJ(3, R3);              \
        COLJ(4, R4);  COLJ(5, R5);  COLJ(6, R6);  COLJ(7, R7);              \
        COLJ(8, R8);  COLJ(9, R9);  COLJ(10, R10); COLJ(11, R11);           \
        xs++; if (xs >= W48) xs = 0;                                        \
    } while (0)

    for (int so = 0; so < 4; so++) {
        STEP(q0, q1, q2, q3, q4, q5, q6, q7, q8, q9, q10, q11);
        STEP(q1, q2, q3, q4, q5, q6, q7, q8, q9, q10, q11, q0);
        STEP(q2, q3, q4, q5, q6, q7, q8, q9, q10, q11, q0, q1);
        STEP(q3, q4, q5, q6, q7, q8, q9, q10, q11, q0, q1, q2);
        STEP(q4, q5, q6, q7, q8, q9, q10, q11, q0, q1, q2, q3);
        STEP(q5, q6, q7, q8, q9, q10, q11, q0, q1, q2, q3, q4);
        STEP(q6, q7, q8, q9, q10, q11, q0, q1, q2, q3, q4, q5);
        STEP(q7, q8, q9, q10, q11, q0, q1, q2, q3, q4, q5, q6);
        STEP(q8, q9, q10, q11, q0, q1, q2, q3, q4, q5, q6, q7);
        STEP(q9, q10, q11, q0, q1, q2, q3, q4, q5, q6, q7, q8);
        STEP(q10, q11, q0, q1, q2, q3, q4, q5, q6, q7, q8, q9);
        STEP(q11, q0, q1, q2, q3, q4, q5, q6, q7, q8, q9, q10);
    }
#undef STEP
#undef COLJ
#undef DIFF

    if (r < 12) {
        unsigned long long* bt =
            best_part + (size_t)t * HW + (y0 + r) * W48 + x0;
#pragma unroll
        for (int j = 0; j < 12; j++)
            atomicMin(&bt[j], bst[j]);
    }
}

// ---------------------------------------------------------------------------
// gather: reduce per-t partials; gather center pixel of (t+1) patch; write
// output frame + next carry + per-element sq-error.
// ---------------------------------------------------------------------------
__global__ __launch_bounds__(256) void gather_kernel(
    const unsigned long long* __restrict__ best_part,
    const float4* __restrict__ rec4, const float* __restrict__ x,
    const float* __restrict__ walls,
    float4* __restrict__ curnext, float* __restrict__ dout,
    float* __restrict__ err, int step)
{
    int p = blockIdx.x * 256 + threadIdx.x;
    if (p >= HW) return;
    unsigned long long bestv = ~0ULL;
#pragma unroll
    for (int j = 0; j < NT; j++) {
        unsigned long long v = best_part[(size_t)j * HW + p];
        bestv = v < bestv ? v : bestv;
    }
    unsigned int m = (unsigned int)bestv;
    int t = m / HW, q = m % HW;
    float4 v = rec4[(t + 1) * HW + q];
    curnext[p] = v;
    dout[(step + 1) * 3 * HW + 0 * HW + p] = v.x;
    dout[(step + 1) * 3 * HW + 1 * HW + p] = v.y;
    dout[(step + 1) * 3 * HW + 2 * HW + p] = v.z;
    float t0 = x[((step + 1) * 3 + 0) * HW + p];
    float t1 = x[((step + 1) * 3 + 1) * HW + p];
    float t2 = x[((step + 1) * 3 + 2) * HW + p];
    float t3 = walls[p];
    float e = (v.x - t0) * (v.x - t0) + (v.y - t1) * (v.y - t1) +
              (v.z - t2) * (v.z - t2) + (v.w - t3) * (v.w - t3);
    err[step * HW + p] = e;
}

// ---------------------------------------------------------------------------
// loss: deterministic reduction; loss = total / 18432.
// ---------------------------------------------------------------------------
__global__ __launch_bounds__(256) void loss_kernel(
    const float* __restrict__ err, float* __restrict__ dout)
{
    __shared__ float ssum[256];
    float s = 0.f;
    for (int i = threadIdx.x; i < 2 * HW; i += 256) s += err[i];
    ssum[threadIdx.x] = s;
    __syncthreads();
    for (int w = 128; w > 0; w >>= 1) {
        if (threadIdx.x < w) ssum[threadIdx.x] += ssum[threadIdx.x + w];
        __syncthreads();
    }
    if (threadIdx.x == 0) dout[9 * HW] = ssum[0] / 18432.0f;
}

extern "C" void kernel_launch(void* const* d_in, const int* in_sizes, int n_in,
                              void* d_out, int out_size, void* d_ws,
                              size_t ws_size, hipStream_t stream)
{
    const float* x     = (const float*)d_in[0];
    const float* rec   = (const float*)d_in[1];
    const float* walls = (const float*)d_in[2];
    float* dout = (float*)d_out;

    char* ws = (char*)d_ws;
    float4* rec4 = (float4*)ws;                               // 589824 B
    float4* curb = (float4*)(ws + 589824);                    // 110592 B
    float*  err  = (float*)(ws + 589824 + 110592);            //  18432 B
    unsigned long long* best_part =
        (unsigned long long*)(ws + 589824 + 110592 + 18432);  // 276480 B

    prep_kernel<<<144, 256, 0, stream>>>(x, rec, walls, rec4, curb, dout);
    for (int step = 0; step < 2; step++) {
        hipMemsetAsync(best_part, 0xFF, (size_t)NT * HW * 8, stream);
        dist_kernel<<<NT * W48 * 4, 64, 0, stream>>>(rec4, curb + step * HW,
                                                     best_part);
        gather_kernel<<<9, 256, 0, stream>>>(best_part, rec4, x, walls,
                                             curb + (step + 1) * HW, dout, err,
                                             step);
    }
    loss_kernel<<<1, 256, 0, stream>>>(err, dout);
}

// Round 9
// 165.389 us; speedup vs baseline: 5.6859x; 5.6859x over previous
//
#include <hip/hip_runtime.h>

#define HW 2304
#define W48 48
#define NT 15              // timestep partials for the atomic spread
#define RS_STRIDE 52       // Rs row stride in floats
#define RS_ROWS 28         // F-local rows 0..27 = query rows yh*24 + (l-2)
#define RS_SIZE (RS_ROWS * RS_STRIDE)

// ---------------------------------------------------------------------------
// prep: build rec_ext (float4: c0,c1,c2,walls) for all 16 timesteps,
//       build cur0 (frame 0 + walls), copy frame 0 (3ch) to d_out.
// ---------------------------------------------------------------------------
__global__ __launch_bounds__(256) void prep_kernel(
    const float* __restrict__ x, const float* __restrict__ rec,
    const float* __restrict__ walls,
    float4* __restrict__ rec4, float4* __restrict__ cur0,
    float* __restrict__ dout)
{
    int id = blockIdx.x * 256 + threadIdx.x;
    if (id < 16 * HW) {
        int t = id / HW, p = id % HW;
        rec4[id] = make_float4(rec[(t * 3 + 0) * HW + p],
                               rec[(t * 3 + 1) * HW + p],
                               rec[(t * 3 + 2) * HW + p],
                               walls[p]);
    }
    if (id < HW) {
        cur0[id] = make_float4(x[0 * HW + id], x[1 * HW + id], x[2 * HW + id],
                               walls[id]);
    }
    if (id < 3 * HW) {
        dout[id] = x[id];  // frame 0, channels 0..2
    }
}

// ---------------------------------------------------------------------------
// dist v9: block = (t, sy, y-half), 1440 blocks x 448 threads (7 waves).
// Small-footprint re-parameterization of the proven r5-r7 structure:
//  - thread owns 3 px: 28 F-rows x 16 col-groups (rows of 16 threads are
//    wave-aligned -> ds_bpermute halo), state ~55 VGPR (no spill by constr.)
//  - LDS = Rs double buffer only (11.6 KB) -> ~4 blocks/CU = 4 independent
//    barrier groups to hide each other's per-sx latency chains.
//  - y-half split: F rows = 24 outputs + 4 halo (1.17x redundancy); Rs halo
//    rows are real rows -> no wrap duplication.
//  - 4-slot NAMED register ring for rec cols (stamped literal rotations).
// F/R/D expressions and summation order bit-identical to rounds 2..7.
// ---------------------------------------------------------------------------
__global__ __launch_bounds__(448, 7) void dist_kernel(
    const float4* __restrict__ rec4, const float4* __restrict__ cur4,
    unsigned long long* __restrict__ best_part)
{
    __shared__ float Rs[2 * RS_SIZE];      // 11648 B

    const int tid = threadIdx.x;
    const int b   = blockIdx.x;
    const int t   = b / 96;
    const int rem = b % 96;
    const int sy  = rem >> 1;
    const int yh  = rem & 1;

    // A ownership: F-local row rid (0..27), cols x0..x0+2
    const int rid = tid >> 4;
    const int cA  = tid & 15;
    const int x0  = 3 * cA;
    int qy = yh * 24 + rid - 2;
    if (qy < 0) qy += W48;
    if (qy >= W48) qy -= W48;
    int ry = qy + sy; if (ry >= W48) ry -= W48;

    const int lane  = tid & 63;
    const int addrL = ((lane & ~15) | ((cA + 15) & 15)) << 2;
    const int addrR = ((lane & ~15) | ((cA + 1) & 15)) << 2;

    const float4* curRow = cur4 + qy * W48;
    const float4 cw0 = curRow[x0 + 0];
    const float4 cw1 = curRow[x0 + 1];
    const float4 cw2 = curRow[x0 + 2];

    const float4* recRow = rec4 + t * HW + ry * W48;
    float4 q0 = recRow[x0 + 0];
    float4 q1 = recRow[x0 + 1];
    float4 q2 = recRow[x0 + 2];
    float4 q3;
    { int c3 = x0 + 3; if (c3 >= W48) c3 -= W48; q3 = recRow[c3]; }
    int nc = x0 + 4; if (nc >= W48) nc -= W48;

    // C ownership (tid < 384): col xc, output rows qyB..qyB+2
    const bool cact = tid < 384;
    const int xc  = tid % W48;
    const int y0C = 3 * (tid / W48);
    const int qyB = yh * 24 + y0C;
    unsigned int mb0 = 0, mb1 = 0, mb2 = 0;
    if (cact) {
        int o0 = qyB + 0 + sy; if (o0 >= W48) o0 -= W48;
        int o1 = qyB + 1 + sy; if (o1 >= W48) o1 -= W48;
        int o2 = qyB + 2 + sy; if (o2 >= W48) o2 -= W48;
        mb0 = (unsigned)(t * HW + o0 * W48);
        mb1 = (unsigned)(t * HW + o1 * W48);
        mb2 = (unsigned)(t * HW + o2 * W48);
    }
    int rx = xc;                               // candidate col (xc+sx)%48

    unsigned long long bst0 = ~0ULL, bst1 = ~0ULL, bst2 = ~0ULL;

#define DIFF(D, C, Wv) do {                                                 \
        float d0 = (C).x - (Wv).x, d1 = (C).y - (Wv).y,                     \
              d2 = (C).z - (Wv).z, d3 = (C).w - (Wv).w;                     \
        D = d0 * d0 + d1 * d1 + d2 * d2 + d3 * d3;                          \
    } while (0)

#define STEP(P, A0, A1, A2) do {                                            \
        float F0, F1, F2;                                                   \
        DIFF(F0, cw0, A0); DIFF(F1, cw1, A1); DIFF(F2, cw2, A2);            \
        float Fm2 = __int_as_float(                                         \
            __builtin_amdgcn_ds_bpermute(addrL, __float_as_int(F1)));       \
        float Fm1 = __int_as_float(                                         \
            __builtin_amdgcn_ds_bpermute(addrL, __float_as_int(F2)));       \
        float F3  = __int_as_float(                                         \
            __builtin_amdgcn_ds_bpermute(addrR, __float_as_int(F0)));       \
        float F4  = __int_as_float(                                         \
            __builtin_amdgcn_ds_bpermute(addrR, __float_as_int(F1)));       \
        float R0 = Fm2 + Fm1 + F0 + F1 + F2;                                \
        float R1 = Fm1 + F0 + F1 + F2 + F3;                                 \
        float R2 = F0 + F1 + F2 + F3 + F4;                                  \
        {                                                                   \
            float* w = &Rs[(P) * RS_SIZE + rid * RS_STRIDE + x0];           \
            w[0] = R0; w[1] = R1; w[2] = R2;                                \
        }                                                                   \
        A0 = recRow[nc];            /* refill retiring slot (used sx+2) */  \
        nc++; if (nc >= W48) nc -= W48;                                     \
        __syncthreads();                                                    \
        if (cact) {                                                         \
            const float* rp = &Rs[(P) * RS_SIZE + y0C * RS_STRIDE + xc];    \
            float rv0 = rp[0],   rv1 = rp[52],  rv2 = rp[104];              \
            float rv3 = rp[156], rv4 = rp[208], rv5 = rp[260];              \
            float rv6 = rp[312];                                            \
            float D0 = rv0 + rv1 + rv2 + rv3 + rv4;                         \
            float D1 = rv1 + rv2 + rv3 + rv4 + rv5;                         \
            float D2 = rv2 + rv3 + rv4 + rv5 + rv6;                         \
            unsigned long long pk;                                          \
            pk = ((unsigned long long)__float_as_uint(D0) << 32) |          \
                 (mb0 + (unsigned)rx);                                      \
            bst0 = pk < bst0 ? pk : bst0;                                   \
            pk = ((unsigned long long)__float_as_uint(D1) << 32) |          \
                 (mb1 + (unsigned)rx);                                      \
            bst1 = pk < bst1 ? pk : bst1;                                   \
            pk = ((unsigned long long)__float_as_uint(D2) << 32) |          \
                 (mb2 + (unsigned)rx);                                      \
            bst2 = pk < bst2 ? pk : bst2;                                   \
        }                                                                   \
        rx++; if (rx >= W48) rx -= W48;                                     \
    } while (0)

    for (int it = 0; it < 12; it++) {
        STEP(0, q0, q1, q2);
        STEP(1, q1, q2, q3);
        STEP(0, q2, q3, q0);
        STEP(1, q3, q0, q1);
    }
#undef STEP
#undef DIFF

    if (cact) {
        unsigned long long* bt = best_part + (size_t)t * HW + qyB * W48 + xc;
        atomicMin(&bt[0 * W48], bst0);
        atomicMin(&bt[1 * W48], bst1);
        atomicMin(&bt[2 * W48], bst2);
    }
}

// ---------------------------------------------------------------------------
// gather: reduce per-t partials; gather center pixel of (t+1) patch; write
// output frame + next carry + per-element sq-error.
// ---------------------------------------------------------------------------
__global__ __launch_bounds__(256) void gather_kernel(
    const unsigned long long* __restrict__ best_part,
    const float4* __restrict__ rec4, const float* __restrict__ x,
    const float* __restrict__ walls,
    float4* __restrict__ curnext, float* __restrict__ dout,
    float* __restrict__ err, int step)
{
    int p = blockIdx.x * 256 + threadIdx.x;
    if (p >= HW) return;
    unsigned long long bestv = ~0ULL;
#pragma unroll
    for (int j = 0; j < NT; j++) {
        unsigned long long v = best_part[(size_t)j * HW + p];
        bestv = v < bestv ? v : bestv;
    }
    unsigned int m = (unsigned int)bestv;
    int t = m / HW, q = m % HW;
    float4 v = rec4[(t + 1) * HW + q];
    curnext[p] = v;
    dout[(step + 1) * 3 * HW + 0 * HW + p] = v.x;
    dout[(step + 1) * 3 * HW + 1 * HW + p] = v.y;
    dout[(step + 1) * 3 * HW + 2 * HW + p] = v.z;
    float t0 = x[((step + 1) * 3 + 0) * HW + p];
    float t1 = x[((step + 1) * 3 + 1) * HW + p];
    float t2 = x[((step + 1) * 3 + 2) * HW + p];
    float t3 = walls[p];
    float e = (v.x - t0) * (v.x - t0) + (v.y - t1) * (v.y - t1) +
              (v.z - t2) * (v.z - t2) + (v.w - t3) * (v.w - t3);
    err[step * HW + p] = e;
}

// ---------------------------------------------------------------------------
// loss: deterministic reduction; loss = total / 18432.
// ---------------------------------------------------------------------------
__global__ __launch_bounds__(256) void loss_kernel(
    const float* __restrict__ err, float* __restrict__ dout)
{
    __shared__ float ssum[256];
    float s = 0.f;
    for (int i = threadIdx.x; i < 2 * HW; i += 256) s += err[i];
    ssum[threadIdx.x] = s;
    __syncthreads();
    for (int w = 128; w > 0; w >>= 1) {
        if (threadIdx.x < w) ssum[threadIdx.x] += ssum[threadIdx.x + w];
        __syncthreads();
    }
    if (threadIdx.x == 0) dout[9 * HW] = ssum[0] / 18432.0f;
}

extern "C" void kernel_launch(void* const* d_in, const int* in_sizes, int n_in,
                              void* d_out, int out_size, void* d_ws,
                              size_t ws_size, hipStream_t stream)
{
    const float* x     = (const float*)d_in[0];
    const float* rec   = (const float*)d_in[1];
    const float* walls = (const float*)d_in[2];
    float* dout = (float*)d_out;

    char* ws = (char*)d_ws;
    float4* rec4 = (float4*)ws;                               // 589824 B
    float4* curb = (float4*)(ws + 589824);                    // 110592 B
    float*  err  = (float*)(ws + 589824 + 110592);            //  18432 B
    unsigned long long* best_part =
        (unsigned long long*)(ws + 589824 + 110592 + 18432);  // 276480 B

    prep_kernel<<<144, 256, 0, stream>>>(x, rec, walls, rec4, curb, dout);
    for (int step = 0; step < 2; step++) {
        hipMemsetAsync(best_part, 0xFF, (size_t)NT * HW * 8, stream);
        dist_kernel<<<NT * W48 * 2, 448, 0, stream>>>(rec4, curb + step * HW,
                                                      best_part);
        gather_kernel<<<9, 256, 0, stream>>>(best_part, rec4, x, walls,
                                             curb + (step + 1) * HW, dout, err,
                                             step);
    }
    loss_kernel<<<1, 256, 0, stream>>>(err, dout);
}